// Round 4
// baseline (48.900 us; speedup 1.0000x reference)
//
#include <hip/hip_runtime.h>

constexpr int FEAT = 512;          // feature dim
constexpr int NCLS = 50000;        // classes
constexpr int B    = 8192;         // batch
constexpr float ALPHA_F = 0.1f;
constexpr int NBINS = 256;

typedef float f32x4 __attribute__((ext_vector_type(4)));

// ---------------------------------------------------------------------------
// ws layout (4B elems):
//   [0, NCLS)          head  (int)   per-class list head, -1 = empty
//   [NCLS, NCLS+B)     next  (int)   linked list
//   [NCLS+B, +NBINS)   bins  (float) loss partial bins
// ---------------------------------------------------------------------------

__global__ void k_init(int* __restrict__ head, float* __restrict__ bins) {
    int i = blockIdx.x * blockDim.x + threadIdx.x;
    if (i < NCLS / 4) ((int4*)head)[i] = make_int4(-1, -1, -1, -1);
    if (i < NBINS) bins[i] = 0.0f;
}

__global__ void k_build(const int* __restrict__ labels,
                        int* __restrict__ head, int* __restrict__ next) {
    int i = blockIdx.x * blockDim.x + threadIdx.x;
    if (i < B) next[i] = atomicExch(&head[labels[i]], i);
}

// realigned +1-dword row store (float4 body), non-temporal
__device__ __forceinline__ void store_row(float* __restrict__ orow,
                                          float4 n0, float4 n1, int lane) {
    const float bx = __shfl(n1.x, 0);
    const float by = __shfl(n1.y, 0);
    const float bz = __shfl(n1.z, 0);
    float x0 = __shfl_down(n0.x, 1), y0 = __shfl_down(n0.y, 1), z0 = __shfl_down(n0.z, 1);
    float x1 = __shfl_down(n1.x, 1), y1 = __shfl_down(n1.y, 1), z1 = __shfl_down(n1.z, 1);
    if (lane == 63) { x0 = bx; y0 = by; z0 = bz; }

    if (lane == 0) {
        __builtin_nontemporal_store(n0.x, orow + 0);
        __builtin_nontemporal_store(n0.y, orow + 1);
        __builtin_nontemporal_store(n0.z, orow + 2);
    }
    f32x4* oa = (f32x4*)(orow + 3);            // 16B aligned
    __builtin_nontemporal_store((f32x4){n0.w, x0, y0, z0}, oa + lane);
    if (lane < 63)
        __builtin_nontemporal_store((f32x4){n1.w, x1, y1, z1}, oa + 64 + lane);
    if (lane == 63)
        __builtin_nontemporal_store(n1.w, orow + 511);
}

// Two adjacent classes per wave: doubles outstanding loads, halves wave count.
__global__ void __launch_bounds__(256)
k_class(const float* __restrict__ centers,
        const float* __restrict__ features,
        const int* __restrict__ head,
        const int* __restrict__ next,
        float* __restrict__ out,          // [0]=loss, +1 = new_centers
        float* __restrict__ bins) {
    const int w    = (int)((blockIdx.x * 256 + threadIdx.x) >> 6);  // wave id
    const int lane = threadIdx.x & 63;
    const int cA   = w * 2;
    if (cA >= NCLS) return;
    const int cB   = cA + 1;

    // issue all independent loads up front
    const float4* cA4 = (const float4*)(centers + (size_t)cA * FEAT);
    const float4* cB4 = (const float4*)(centers + (size_t)cB * FEAT);
    const float4 aA0 = cA4[lane];
    const float4 aA1 = cA4[lane + 64];
    const float4 aB0 = cB4[lane];
    const float4 aB1 = cB4[lane + 64];
    const int hA = __builtin_amdgcn_readfirstlane(head[cA]);
    const int hB = __builtin_amdgcn_readfirstlane(head[cB]);

    float4 SA0 = {0,0,0,0}, SA1 = {0,0,0,0};
    float4 SB0 = {0,0,0,0}, SB1 = {0,0,0,0};
    float loss = 0.0f;
    int cntA = 0, cntB = 0;

    for (int j = hA; j >= 0; j = __builtin_amdgcn_readfirstlane(next[j]), ++cntA) {
        const float4* f4 = (const float4*)(features + (size_t)j * FEAT);
        const float4 f0 = f4[lane];
        const float4 f1 = f4[lane + 64];
        SA0.x += f0.x; SA0.y += f0.y; SA0.z += f0.z; SA0.w += f0.w;
        SA1.x += f1.x; SA1.y += f1.y; SA1.z += f1.z; SA1.w += f1.w;
        float d;
        d = f0.x - aA0.x; loss += d * d;
        d = f0.y - aA0.y; loss += d * d;
        d = f0.z - aA0.z; loss += d * d;
        d = f0.w - aA0.w; loss += d * d;
        d = f1.x - aA1.x; loss += d * d;
        d = f1.y - aA1.y; loss += d * d;
        d = f1.z - aA1.z; loss += d * d;
        d = f1.w - aA1.w; loss += d * d;
    }
    for (int j = hB; j >= 0; j = __builtin_amdgcn_readfirstlane(next[j]), ++cntB) {
        const float4* f4 = (const float4*)(features + (size_t)j * FEAT);
        const float4 f0 = f4[lane];
        const float4 f1 = f4[lane + 64];
        SB0.x += f0.x; SB0.y += f0.y; SB0.z += f0.z; SB0.w += f0.w;
        SB1.x += f1.x; SB1.y += f1.y; SB1.z += f1.z; SB1.w += f1.w;
        float d;
        d = f0.x - aB0.x; loss += d * d;
        d = f0.y - aB0.y; loss += d * d;
        d = f0.z - aB0.z; loss += d * d;
        d = f0.w - aB0.w; loss += d * d;
        d = f1.x - aB1.x; loss += d * d;
        d = f1.y - aB1.y; loss += d * d;
        d = f1.z - aB1.z; loss += d * d;
        d = f1.w - aB1.w; loss += d * d;
    }

    float4 nA0, nA1, nB0, nB1;
    if (cntA > 0) {
        const float s = 1.0f - ALPHA_F, v = ALPHA_F / (float)cntA;
        nA0 = make_float4(aA0.x*s + SA0.x*v, aA0.y*s + SA0.y*v, aA0.z*s + SA0.z*v, aA0.w*s + SA0.w*v);
        nA1 = make_float4(aA1.x*s + SA1.x*v, aA1.y*s + SA1.y*v, aA1.z*s + SA1.z*v, aA1.w*s + SA1.w*v);
    } else { nA0 = aA0; nA1 = aA1; }
    if (cntB > 0) {
        const float s = 1.0f - ALPHA_F, v = ALPHA_F / (float)cntB;
        nB0 = make_float4(aB0.x*s + SB0.x*v, aB0.y*s + SB0.y*v, aB0.z*s + SB0.z*v, aB0.w*s + SB0.w*v);
        nB1 = make_float4(aB1.x*s + SB1.x*v, aB1.y*s + SB1.y*v, aB1.z*s + SB1.z*v, aB1.w*s + SB1.w*v);
    } else { nB0 = aB0; nB1 = aB1; }

    // single wave-reduce for both classes' loss
#pragma unroll
    for (int off = 32; off > 0; off >>= 1)
        loss += __shfl_down(loss, off);
    if (lane == 0 && (cntA + cntB) > 0)
        atomicAdd(&bins[w & (NBINS - 1)], loss);

    store_row(out + 1 + (size_t)cA * FEAT, nA0, nA1, lane);
    store_row(out + 1 + (size_t)cB * FEAT, nB0, nB1, lane);
}

__global__ void k_fin(const float* __restrict__ bins, float* __restrict__ out) {
    const int t = threadIdx.x;        // 256 threads = 4 waves
    float s = bins[t];
#pragma unroll
    for (int off = 32; off > 0; off >>= 1)
        s += __shfl_down(s, off);
    __shared__ float sm[4];
    if ((t & 63) == 0) sm[t >> 6] = s;
    __syncthreads();
    if (t == 0) out[0] = (sm[0] + sm[1] + sm[2] + sm[3]) / (float)B;
}

extern "C" void kernel_launch(void* const* d_in, const int* in_sizes, int n_in,
                              void* d_out, int out_size, void* d_ws, size_t ws_size,
                              hipStream_t stream) {
    const float* features = (const float*)d_in[0];
    const int*   labels   = (const int*)d_in[1];
    const float* centers  = (const float*)d_in[2];

    float* out  = (float*)d_out;
    int*   head = (int*)d_ws;             // NCLS
    int*   next = head + NCLS;            // B
    float* bins = (float*)(next + B);     // NBINS

    k_init<<<(NCLS / 4 + 255) / 256, 256, 0, stream>>>(head, bins);
    k_build<<<(B + 255) / 256, 256, 0, stream>>>(labels, head, next);
    k_class<<<(NCLS / 2 + 3) / 4, 256, 0, stream>>>(centers, features, head, next, out, bins);
    k_fin<<<1, 256, 0, stream>>>(bins, out);
}